// Round 11
// baseline (449.429 us; speedup 1.0000x reference)
//
#include <hip/hip_runtime.h>

typedef unsigned short u16;
typedef unsigned int u32;
typedef __attribute__((ext_vector_type(8))) short short8;
typedef __attribute__((ext_vector_type(4))) float f32x4;
typedef __attribute__((ext_vector_type(2))) float f32x2;

__device__ __forceinline__ float bf2f(u16 u) {
    return __uint_as_float(((u32)u) << 16);
}
__device__ __forceinline__ u16 f2bf(float f) {
    u32 u = __float_as_uint(f);
    u += 0x7fff + ((u >> 16) & 1);   // round-to-nearest-even
    return (u16)(u >> 16);
}
__device__ __forceinline__ u32 pack2(float a, float b) {
    return (u32)f2bf(a) | ((u32)f2bf(b) << 16);
}
// pack 4 floats -> 4 fp8 e4m3 in one u32
__device__ __forceinline__ u32 pk_fp8x4(float f0, float f1, float f2, float f3) {
    int w = __builtin_amdgcn_cvt_pk_fp8_f32(f0, f1, 0, false);
    w = __builtin_amdgcn_cvt_pk_fp8_f32(f2, f3, w, true);
    return (u32)w;
}
// accumulate 4 fp8 (one u32) into a[0..3]
__device__ __forceinline__ void acc4(float* a, u32 w) {
    f32x2 lo = __builtin_amdgcn_cvt_pk_f32_fp8((int)w, false);
    f32x2 hi = __builtin_amdgcn_cvt_pk_f32_fp8((int)w, true);
    a[0] += lo.x; a[1] += lo.y; a[2] += hi.x; a[3] += hi.y;
}
__device__ __forceinline__ void acc4m(float* a, u32 w, float m) {
    f32x2 lo = __builtin_amdgcn_cvt_pk_f32_fp8((int)w, false);
    f32x2 hi = __builtin_amdgcn_cvt_pk_f32_fp8((int)w, true);
    a[0] += m * lo.x; a[1] += m * lo.y; a[2] += m * hi.x; a[3] += m * hi.y;
}
__device__ __forceinline__ void acc16(float* a, uint4 v) {
    acc4(a + 0, v.x); acc4(a + 4, v.y); acc4(a + 8, v.z); acc4(a + 12, v.w);
}
__device__ __forceinline__ void acc16m(float* a, uint4 v, float m) {
    acc4m(a + 0, v.x, m); acc4m(a + 4, v.y, m); acc4m(a + 8, v.z, m); acc4m(a + 12, v.w, m);
}

// ---------------- merged prep: cvt_x | cvt_w | hist (branch on blockIdx range) ----------------

__global__ __launch_bounds__(256) void prep_kernel(const float* __restrict__ x,
                                                   u16* __restrict__ xb, u32* __restrict__ xq,
                                                   int n, int nx,
                                                   const float* __restrict__ WA,
                                                   const float* __restrict__ WB,
                                                   const float* __restrict__ As,
                                                   const float* __restrict__ Bs,
                                                   u16* __restrict__ wT, int nlayers, int nw,
                                                   const int* __restrict__ dst,
                                                   int* __restrict__ ccnt, int e, int nb) {
    __shared__ int h[256];
    int b = blockIdx.x;
    int tid = threadIdx.x;
    if (b < nx) {
        // ---- cvt_x ----
        int i = b * 256 + tid;                    // group of 4 elements
        int row = i >> 6;                         // 64 groups per 256-wide row
        ushort4 o;
        u32 q;
        if (row < n) {
            float4 v = ((const float4*)x)[i];
            o.x = f2bf(v.x); o.y = f2bf(v.y); o.z = f2bf(v.z); o.w = f2bf(v.w);
            q = pk_fp8x4(v.x, v.y, v.z, v.w);
        } else {
            o.x = o.y = o.z = o.w = 0;
            q = 0;
        }
        ((ushort4*)xb)[i] = o;
        xq[i] = q;
    } else if (b < nx + nw) {
        // ---- cvt_w ----
        int i = (b - nx) * 256 + tid;
        const int per = 256 * 512;
        if (i >= nlayers * per) return;
        int l = i / per;
        int rem = i - l * per;
        int nn = rem >> 9;
        int k = rem & 511;
        const float* Aw = (l == 0) ? WA : As + (size_t)(l - 1) * 65536;
        const float* Bw = (l == 0) ? WB : Bs + (size_t)(l - 1) * 65536;
        float v = (k < 256) ? Aw[(size_t)k * 256 + nn] : Bw[(size_t)(k - 256) * 256 + nn];
        wT[i] = f2bf(v);
    } else {
        // ---- hist ----
        h[tid] = 0;
        __syncthreads();
        int e0 = (b - nx - nw) * 4096;
#pragma unroll
        for (int j = 0; j < 16; ++j) {
            int i = e0 + j * 256 + tid;
            if (i < e) atomicAdd(&h[dst[i] >> 8], 1);
        }
        __syncthreads();
        if (tid < nb) {
            int v = h[tid];
            if (v) atomicAdd(&ccnt[tid], v);
        }
    }
}

// ---------------- CSR build: two-level counting sort ----------------
// Requires N <= 65536 so an edge packs into u32 as (dst<<16)|src.
// Coarse bucket b covers nodes [b*256, b*256+256).

__global__ __launch_bounds__(256) void scan_coarse_kernel(const int* __restrict__ ccnt,
                                                          int* __restrict__ cbase,
                                                          int* __restrict__ rowptr,
                                                          int nb, int n, int e) {
    __shared__ int sh[256];
    int t = threadIdx.x;
    int v = (t < nb) ? ccnt[t] : 0;
    int x = v;
    sh[t] = x; __syncthreads();
    for (int o = 1; o < 256; o <<= 1) {
        int y = (t >= o) ? sh[t - o] : 0;
        __syncthreads();
        x += y; sh[t] = x; __syncthreads();
    }
    if (t < nb) cbase[t] = x - v;
    if (t == 0) { cbase[nb] = e; rowptr[n] = e; }
}

__global__ __launch_bounds__(256) void passA_kernel(const int* __restrict__ src,
                                                    const int* __restrict__ dst,
                                                    const int* __restrict__ cbase,
                                                    int* __restrict__ cfill,
                                                    u32* __restrict__ tmp, int e, int nb) {
    __shared__ int ph[256], pb[256], pr[256], cb[256];
    __shared__ u32 ed[4096];
    int tid = threadIdx.x;
    ph[tid] = 0; pr[tid] = 0;
    cb[tid] = (tid < nb) ? cbase[tid] : 0;
    __syncthreads();
    int e0 = blockIdx.x * 4096;
#pragma unroll
    for (int j = 0; j < 16; ++j) {
        int i = e0 + j * 256 + tid;
        u32 p = 0xFFFFFFFFu;
        if (i < e) {
            int d = dst[i];
            p = ((u32)d << 16) | (u32)src[i];
            atomicAdd(&ph[d >> 8], 1);
        }
        ed[j * 256 + tid] = p;
    }
    __syncthreads();
    pb[tid] = (tid < nb && ph[tid]) ? atomicAdd(&cfill[tid], ph[tid]) : 0;
    __syncthreads();
#pragma unroll
    for (int j = 0; j < 16; ++j) {
        u32 p = ed[j * 256 + tid];
        if (p != 0xFFFFFFFFu) {
            int bk = p >> 24;
            int r = atomicAdd(&pr[bk], 1);
            tmp[cb[bk] + pb[bk] + r] = p;
        }
    }
}

__global__ __launch_bounds__(256) void passB_kernel(const u32* __restrict__ tmp,
                                                    const int* __restrict__ cbase,
                                                    int* __restrict__ rowptr,
                                                    float* __restrict__ invd,
                                                    int* __restrict__ srcs, int n) {
    __shared__ int h[256], loc[256], cnt2[256], sh[256];
    int b = blockIdx.x;
    int tid = threadIdx.x;
    int base = cbase[b];
    int cnt = cbase[b + 1] - base;
    int node0 = b << 8;
    h[tid] = 0; cnt2[tid] = 0;
    __syncthreads();
    for (int i = tid; i < cnt; i += 256)
        atomicAdd(&h[(tmp[base + i] >> 16) & 255], 1);
    __syncthreads();
    int c = h[tid];
    int x = c;
    sh[tid] = x; __syncthreads();
    for (int o = 1; o < 256; o <<= 1) {
        int y = (tid >= o) ? sh[tid - o] : 0;
        __syncthreads();
        x += y; sh[tid] = x; __syncthreads();
    }
    loc[tid] = x - c;   // exclusive offset within bucket
    int node = node0 + tid;
    if (node < n) {
        rowptr[node] = base + x - c;
        invd[node] = 1.0f / (float)(c > 0 ? c : 1);
    }
    __syncthreads();
    for (int i = tid; i < cnt; i += 256) {
        u32 p = tmp[base + i];
        int ln = (p >> 16) & 255;
        int r = atomicAdd(&cnt2[ln], 1);
        srcs[base + loc[ln] + r] = (int)(p & 0xffffu);
    }
}

// ---------------- mean aggregation: one wave per node, fp8 gather ----------------
// fp8 row = 256B; 16 lanes x 16B cover a row; 4 edges per wave-load, x2 unroll
// -> 8 edges in flight. Output mean row written as bf16 to mb.
// (Kept as a standalone dispatch: fusing this into the GEMM (R3/R4) serializes gather
//  behind GEMM phases within each block and loses ~2.4x effective gather rate.)

__global__ __launch_bounds__(256) void agg_kernel(const unsigned char* __restrict__ q,
                                                  u16* __restrict__ mb,
                                                  const int* __restrict__ rowptr,
                                                  const int* __restrict__ srcs,
                                                  const float* __restrict__ invd,
                                                  int n, int npad) {
    int gw = (blockIdx.x * 256 + threadIdx.x) >> 6;  // node id
    int lane = threadIdx.x & 63;
    int qd = lane >> 4;          // edge slot within group of 4
    int fl = lane & 15;          // 16B chunk (16 feats) within the row
    if (gw >= npad) return;
    u16* orow = mb + (size_t)gw * 256;
    if (gw >= n) {
        if (lane < 16) {
            uint4 z; z.x = z.y = z.z = z.w = 0;
            uint4* p = (uint4*)(orow + lane * 16);
            p[0] = z; p[1] = z;
        }
        return;
    }
    int beg = rowptr[gw], end = rowptr[gw + 1];
    float a[16];
#pragma unroll
    for (int i = 0; i < 16; ++i) a[i] = 0.f;
    for (int base = beg; base < end; base += 64) {
        int cnt = end - base;
        if (cnt > 64) cnt = 64;
        int el = (lane < cnt) ? srcs[base + lane] : 0;
        int t = 0;
        for (; 4 * t + 8 <= cnt; t += 2) {
            int s0 = __shfl(el, 4 * t + qd);
            int s1 = __shfl(el, 4 * t + 4 + qd);
            uint4 v0 = *(const uint4*)(q + (size_t)s0 * 256 + fl * 16);
            uint4 v1 = *(const uint4*)(q + (size_t)s1 * 256 + fl * 16);
            acc16(a, v0);
            acc16(a, v1);
        }
        for (; 4 * t < cnt; ++t) {
            int ei = 4 * t + qd;
            int sj = __shfl(el, ei & 63);
            float m = (ei < cnt) ? 1.0f : 0.0f;
            uint4 v = *(const uint4*)(q + (size_t)sj * 256 + fl * 16);
            acc16m(a, v, m);
        }
    }
    // reduce the 4 quarters
#pragma unroll
    for (int i = 0; i < 16; ++i) {
        a[i] += __shfl_xor(a[i], 16);
        a[i] += __shfl_xor(a[i], 32);
    }
    if (lane < 16) {
        float sc = invd[gw];
        uint4 o0, o1;
        o0.x = pack2(a[0] * sc, a[1] * sc);
        o0.y = pack2(a[2] * sc, a[3] * sc);
        o0.z = pack2(a[4] * sc, a[5] * sc);
        o0.w = pack2(a[6] * sc, a[7] * sc);
        o1.x = pack2(a[8] * sc, a[9] * sc);
        o1.y = pack2(a[10] * sc, a[11] * sc);
        o1.z = pack2(a[12] * sc, a[13] * sc);
        o1.w = pack2(a[14] * sc, a[15] * sc);
        uint4* p = (uint4*)(orow + lane * 16);
        p[0] = o0; p[1] = o1;
    }
}

// ---------------- GEMM: out = act([m | cur] @ wT^T), 64x256 tile, NO-LDS register GEMM ----
// Barrier-free K-loop, fragments global->VGPR (B: zero cross-wave reuse; A: L2-captured).
// R10 post-mortem: launch_bounds(256,4) => unified budget 128; acc eats 64 AGPRs leaving
// 64 arch VGPRs -> compiler couldn't pipeline, loads serialized (72us, MfmaUtil 6.7).
// Occupancy is grid-capped at 784/256 ~ 3 blocks/CU anyway, so: launch_bounds(256,3)
// (12 waves/CU = the grid cap, budget ~170 regs) + EXPLICIT 2-stage register pipeline:
// two named fragment sets, LOAD(ks+1) issued before MFMA(ks) so each step's L2 latency
// hides under 16 MFMAs. ~148 regs total, no spill expected.
// cur/outb NEVER alias (hb0/hb1 ping-pong in launcher — R9 race fix).
// A: rows from m (ks<8) then cur (ks>=8), both [NPAD][256] bf16 row-major.
// B: wT layer slice [n=256][k=512] bf16, k-contiguous. Wave w owns cols w*64..w*64+63.
// fin=0: store h as bf16 (outb) AND fp8 (hqb) -- feeds next round's agg (next dispatch).
// fin=1: sigmoid, dot rows against wo (fp32 [256]) + bias -> out[row].

__global__ __launch_bounds__(256, 3) void gemm_kernel(const u16* __restrict__ mA,
                                                      const u16* __restrict__ cur,
                                                      const u16* __restrict__ wT,
                                                      u16* __restrict__ outb,
                                                      unsigned char* __restrict__ hqb,
                                                      const float* __restrict__ wo,
                                                      const float* __restrict__ bo,
                                                      float* __restrict__ out,
                                                      int n, int apply_sigmoid, int fin) {
    __shared__ float lO[4][64];
    int r0 = blockIdx.x * 64;
    int tid = threadIdx.x;
    int lane = tid & 63;
    int w = tid >> 6;                  // wave id = col group (cols w*64..)
    int lrow = lane & 15, quad = lane >> 4;

    f32x4 acc[4][4] = {};

    // per-lane base pointers (element offsets in u16)
    const u16* bBase = wT + (size_t)(w * 64 + lrow) * 512 + quad * 8;   // + ct*16*512 + ks*32

    short8 aA[4], bA[4], aB[4], bB[4];

    auto LOAD = [&](int ks, short8* a, short8* b) {
        const u16* srcA = (ks < 8) ? mA : cur;
        int kk = (ks * 32) & 255;
        const u16* aBase = srcA + (size_t)(r0 + lrow) * 256 + kk + quad * 8;  // + rt*16*256
#pragma unroll
        for (int rt = 0; rt < 4; ++rt)
            a[rt] = *(const short8*)(aBase + (size_t)rt * 16 * 256);
#pragma unroll
        for (int ct = 0; ct < 4; ++ct)
            b[ct] = *(const short8*)(bBase + (size_t)ct * 16 * 512 + ks * 32);
    };
    auto MFMA = [&](const short8* a, const short8* b) {
#pragma unroll
        for (int rt = 0; rt < 4; ++rt)
#pragma unroll
            for (int ct = 0; ct < 4; ++ct)
                acc[rt][ct] = __builtin_amdgcn_mfma_f32_16x16x32_bf16(a[rt], b[ct], acc[rt][ct], 0, 0, 0);
    };

    LOAD(0, aA, bA);
#pragma unroll
    for (int ks = 0; ks < 16; ks += 2) {
        LOAD(ks + 1, aB, bB);          // in flight while MFMA(ks) runs
        MFMA(aA, bA);
        if (ks + 2 < 16) LOAD(ks + 2, aA, bA);   // in flight while MFMA(ks+1) runs
        MFMA(aB, bB);
    }

    if (!fin) {
#pragma unroll
        for (int rt = 0; rt < 4; ++rt) {
            int rbase = r0 + rt * 16 + quad * 4;
#pragma unroll
            for (int r = 0; r < 4; ++r) {
                int row = rbase + r;
                if (row < n) {
#pragma unroll
                    for (int ct = 0; ct < 4; ++ct) {
                        float v = acc[rt][ct][r];
                        if (apply_sigmoid) v = 1.0f / (1.0f + __expf(-v));
                        int col = w * 64 + ct * 16 + lrow;
                        outb[(size_t)row * 256 + col] = f2bf(v);
                        // fused fp8 emit (replaces a separate cvt_h pass)
                        u32 wq = (u32)__builtin_amdgcn_cvt_pk_fp8_f32(v, v, 0, false);
                        hqb[(size_t)row * 256 + col] = (unsigned char)(wq & 0xff);
                    }
                }
            }
        }
    } else {
        // final layer: sigmoid then dot with wo, reduce, write out
        float wv[4];
#pragma unroll
        for (int ct = 0; ct < 4; ++ct) wv[ct] = wo[w * 64 + ct * 16 + lrow];
#pragma unroll
        for (int rt = 0; rt < 4; ++rt) {
#pragma unroll
            for (int r = 0; r < 4; ++r) {
                float s = 0.f;
#pragma unroll
                for (int ct = 0; ct < 4; ++ct) {
                    float v = acc[rt][ct][r];
                    v = 1.0f / (1.0f + __expf(-v));
                    s += v * wv[ct];
                }
                // reduce across the 16 lanes (lrow bits 0..3) sharing this row
                s += __shfl_xor(s, 1);
                s += __shfl_xor(s, 2);
                s += __shfl_xor(s, 4);
                s += __shfl_xor(s, 8);
                if (lrow == 0) {
                    int rowlocal = rt * 16 + quad * 4 + r;
                    lO[w][rowlocal] = s;
                }
            }
        }
        __syncthreads();
        if (tid < 64) {
            int row = r0 + tid;
            if (row < n)
                out[row] = lO[0][tid] + lO[1][tid] + lO[2][tid] + lO[3][tid] + bo[0];
        }
    }
}

// ---------------- launch ----------------

extern "C" void kernel_launch(void* const* d_in, const int* in_sizes, int n_in,
                              void* d_out, int out_size, void* d_ws, size_t ws_size,
                              hipStream_t stream) {
    const float* x  = (const float*)d_in[0];
    const int*   ei = (const int*)d_in[1];
    const float* WA = (const float*)d_in[2];
    const float* WB = (const float*)d_in[3];
    const float* As = (const float*)d_in[4];
    const float* Bs = (const float*)d_in[5];
    const float* Wo = (const float*)d_in[6];
    const float* bo = (const float*)d_in[7];
    float* out = (float*)d_out;

    const int H = 256;
    int N = in_sizes[0] / H;
    int E = in_sizes[1] / 2;
    int L = in_sizes[4] / (H * H);
    int NPAD = (N + 127) & ~127;
    int NB = (N + 255) >> 8;           // coarse buckets (requires N <= 65536)

    char* wsp = (char*)d_ws;
    size_t off = 0;
    auto alloc = [&](size_t b) { size_t o = off; off += (b + 255) & ~(size_t)255; return o; };
    int*   rowptr = (int*)(wsp + alloc((size_t)(NPAD + 1) * 4));
    int*   ccnt   = (int*)(wsp + alloc(2048));      // ccnt[256] + cfill[256] contiguous
    int*   cfill  = ccnt + 256;
    int*   cbase  = (int*)(wsp + alloc(1032 + 256));
    float* invd   = (float*)(wsp + alloc((size_t)NPAD * 4));
    int*   srcs   = (int*)(wsp + alloc((size_t)E * 4));
    u16*   xb     = (u16*)(wsp + alloc((size_t)NPAD * H * 2));
    u16*   hb0    = (u16*)(wsp + alloc((size_t)NPAD * H * 2));  // h ping
    u16*   hb1    = (u16*)(wsp + alloc((size_t)NPAD * H * 2));  // h pong
    u16*   mb     = (u16*)(wsp + alloc((size_t)NPAD * H * 2));
    u32*   xq     = (u32*)(wsp + alloc((size_t)NPAD * H));      // fp8 x
    u32*   hq     = (u32*)(wsp + alloc((size_t)NPAD * H));      // fp8 h (gemm epilogue)
    u16*   wT     = (u16*)(wsp + alloc((size_t)(L + 1) * 512 * 256 * 2));
    // tmp (packed coarse-sorted edges) aliases mb: dead until first agg writes mb
    u32*   tmp    = (u32*)mb;

    const int* esrc = ei;
    const int* edst = ei + E;

    hipMemsetAsync(ccnt, 0, 2048, stream);

    int gridE = (E + 4095) / 4096;
    int nx = NPAD / 4;
    int nw = ((L + 1) * 512 * 256 + 255) / 256;
    prep_kernel<<<nx + nw + gridE, 256, 0, stream>>>(x, xb, xq, N, nx,
                                                     WA, WB, As, Bs, wT, L + 1, nw,
                                                     edst, ccnt, E, NB);
    scan_coarse_kernel<<<1, 256, 0, stream>>>(ccnt, cbase, rowptr, NB, N, E);
    passA_kernel<<<gridE, 256, 0, stream>>>(esrc, edst, cbase, cfill, tmp, E, NB);
    passB_kernel<<<NB, 256, 0, stream>>>(tmp, cbase, rowptr, invd, srcs, N);

    const u16* cur = xb;
    const unsigned char* curq = (const unsigned char*)xq;
    u16* hnext = hb0;
    for (int s = 0; s <= L; ++s) {
        int fin = (s == L) ? 1 : 0;
        agg_kernel<<<NPAD / 4, 256, 0, stream>>>(curq, mb, rowptr, srcs, invd, N, NPAD);
        gemm_kernel<<<NPAD / 64, 256, 0, stream>>>(mb, cur, wT + (size_t)s * 512 * 256, hnext,
                                                   (unsigned char*)hq, Wo, bo, out, N,
                                                   s > 0 ? 1 : 0, fin);
        if (!fin) {
            cur = hnext;
            curq = (const unsigned char*)hq;
            hnext = (hnext == hb0) ? hb1 : hb0;
        }
    }
}

// Round 12
// 384.801 us; speedup vs baseline: 1.1680x; 1.1680x over previous
//
#include <hip/hip_runtime.h>

typedef unsigned short u16;
typedef unsigned int u32;
typedef __attribute__((ext_vector_type(8))) short short8;
typedef __attribute__((ext_vector_type(4))) float f32x4;
typedef __attribute__((ext_vector_type(2))) float f32x2;

__device__ __forceinline__ float bf2f(u16 u) {
    return __uint_as_float(((u32)u) << 16);
}
__device__ __forceinline__ u16 f2bf(float f) {
    u32 u = __float_as_uint(f);
    u += 0x7fff + ((u >> 16) & 1);   // round-to-nearest-even
    return (u16)(u >> 16);
}
__device__ __forceinline__ u32 pack2(float a, float b) {
    return (u32)f2bf(a) | ((u32)f2bf(b) << 16);
}
// pack 4 floats -> 4 fp8 e4m3 in one u32
__device__ __forceinline__ u32 pk_fp8x4(float f0, float f1, float f2, float f3) {
    int w = __builtin_amdgcn_cvt_pk_fp8_f32(f0, f1, 0, false);
    w = __builtin_amdgcn_cvt_pk_fp8_f32(f2, f3, w, true);
    return (u32)w;
}
// accumulate 4 fp8 (one u32) into a[0..3]
__device__ __forceinline__ void acc4(float* a, u32 w) {
    f32x2 lo = __builtin_amdgcn_cvt_pk_f32_fp8((int)w, false);
    f32x2 hi = __builtin_amdgcn_cvt_pk_f32_fp8((int)w, true);
    a[0] += lo.x; a[1] += lo.y; a[2] += hi.x; a[3] += hi.y;
}
__device__ __forceinline__ void acc4m(float* a, u32 w, float m) {
    f32x2 lo = __builtin_amdgcn_cvt_pk_f32_fp8((int)w, false);
    f32x2 hi = __builtin_amdgcn_cvt_pk_f32_fp8((int)w, true);
    a[0] += m * lo.x; a[1] += m * lo.y; a[2] += m * hi.x; a[3] += m * hi.y;
}
__device__ __forceinline__ void acc16(float* a, uint4 v) {
    acc4(a + 0, v.x); acc4(a + 4, v.y); acc4(a + 8, v.z); acc4(a + 12, v.w);
}
__device__ __forceinline__ void acc16m(float* a, uint4 v, float m) {
    acc4m(a + 0, v.x, m); acc4m(a + 4, v.y, m); acc4m(a + 8, v.z, m); acc4m(a + 12, v.w, m);
}

// ---------------- merged prep: cvt_x | cvt_w | hist (branch on blockIdx range) ----------------

__global__ __launch_bounds__(256) void prep_kernel(const float* __restrict__ x,
                                                   u16* __restrict__ xb, u32* __restrict__ xq,
                                                   int n, int nx,
                                                   const float* __restrict__ WA,
                                                   const float* __restrict__ WB,
                                                   const float* __restrict__ As,
                                                   const float* __restrict__ Bs,
                                                   u16* __restrict__ wT, int nlayers, int nw,
                                                   const int* __restrict__ dst,
                                                   int* __restrict__ ccnt, int e, int nb) {
    __shared__ int h[256];
    int b = blockIdx.x;
    int tid = threadIdx.x;
    if (b < nx) {
        // ---- cvt_x ----
        int i = b * 256 + tid;                    // group of 4 elements
        int row = i >> 6;                         // 64 groups per 256-wide row
        ushort4 o;
        u32 q;
        if (row < n) {
            float4 v = ((const float4*)x)[i];
            o.x = f2bf(v.x); o.y = f2bf(v.y); o.z = f2bf(v.z); o.w = f2bf(v.w);
            q = pk_fp8x4(v.x, v.y, v.z, v.w);
        } else {
            o.x = o.y = o.z = o.w = 0;
            q = 0;
        }
        ((ushort4*)xb)[i] = o;
        xq[i] = q;
    } else if (b < nx + nw) {
        // ---- cvt_w ----
        int i = (b - nx) * 256 + tid;
        const int per = 256 * 512;
        if (i >= nlayers * per) return;
        int l = i / per;
        int rem = i - l * per;
        int nn = rem >> 9;
        int k = rem & 511;
        const float* Aw = (l == 0) ? WA : As + (size_t)(l - 1) * 65536;
        const float* Bw = (l == 0) ? WB : Bs + (size_t)(l - 1) * 65536;
        float v = (k < 256) ? Aw[(size_t)k * 256 + nn] : Bw[(size_t)(k - 256) * 256 + nn];
        wT[i] = f2bf(v);
    } else {
        // ---- hist ----
        h[tid] = 0;
        __syncthreads();
        int e0 = (b - nx - nw) * 4096;
#pragma unroll
        for (int j = 0; j < 16; ++j) {
            int i = e0 + j * 256 + tid;
            if (i < e) atomicAdd(&h[dst[i] >> 8], 1);
        }
        __syncthreads();
        if (tid < nb) {
            int v = h[tid];
            if (v) atomicAdd(&ccnt[tid], v);
        }
    }
}

// ---------------- CSR build: two-level counting sort ----------------
// Requires N <= 65536 so an edge packs into u32 as (dst<<16)|src.
// Coarse bucket b covers nodes [b*256, b*256+256).

__global__ __launch_bounds__(256) void scan_coarse_kernel(const int* __restrict__ ccnt,
                                                          int* __restrict__ cbase,
                                                          int* __restrict__ rowptr,
                                                          int nb, int n, int e) {
    __shared__ int sh[256];
    int t = threadIdx.x;
    int v = (t < nb) ? ccnt[t] : 0;
    int x = v;
    sh[t] = x; __syncthreads();
    for (int o = 1; o < 256; o <<= 1) {
        int y = (t >= o) ? sh[t - o] : 0;
        __syncthreads();
        x += y; sh[t] = x; __syncthreads();
    }
    if (t < nb) cbase[t] = x - v;
    if (t == 0) { cbase[nb] = e; rowptr[n] = e; }
}

__global__ __launch_bounds__(256) void passA_kernel(const int* __restrict__ src,
                                                    const int* __restrict__ dst,
                                                    const int* __restrict__ cbase,
                                                    int* __restrict__ cfill,
                                                    u32* __restrict__ tmp, int e, int nb) {
    __shared__ int ph[256], pb[256], pr[256], cb[256];
    __shared__ u32 ed[4096];
    int tid = threadIdx.x;
    ph[tid] = 0; pr[tid] = 0;
    cb[tid] = (tid < nb) ? cbase[tid] : 0;
    __syncthreads();
    int e0 = blockIdx.x * 4096;
#pragma unroll
    for (int j = 0; j < 16; ++j) {
        int i = e0 + j * 256 + tid;
        u32 p = 0xFFFFFFFFu;
        if (i < e) {
            int d = dst[i];
            p = ((u32)d << 16) | (u32)src[i];
            atomicAdd(&ph[d >> 8], 1);
        }
        ed[j * 256 + tid] = p;
    }
    __syncthreads();
    pb[tid] = (tid < nb && ph[tid]) ? atomicAdd(&cfill[tid], ph[tid]) : 0;
    __syncthreads();
#pragma unroll
    for (int j = 0; j < 16; ++j) {
        u32 p = ed[j * 256 + tid];
        if (p != 0xFFFFFFFFu) {
            int bk = p >> 24;
            int r = atomicAdd(&pr[bk], 1);
            tmp[cb[bk] + pb[bk] + r] = p;
        }
    }
}

__global__ __launch_bounds__(256) void passB_kernel(const u32* __restrict__ tmp,
                                                    const int* __restrict__ cbase,
                                                    int* __restrict__ rowptr,
                                                    float* __restrict__ invd,
                                                    int* __restrict__ srcs, int n) {
    __shared__ int h[256], loc[256], cnt2[256], sh[256];
    int b = blockIdx.x;
    int tid = threadIdx.x;
    int base = cbase[b];
    int cnt = cbase[b + 1] - base;
    int node0 = b << 8;
    h[tid] = 0; cnt2[tid] = 0;
    __syncthreads();
    for (int i = tid; i < cnt; i += 256)
        atomicAdd(&h[(tmp[base + i] >> 16) & 255], 1);
    __syncthreads();
    int c = h[tid];
    int x = c;
    sh[tid] = x; __syncthreads();
    for (int o = 1; o < 256; o <<= 1) {
        int y = (tid >= o) ? sh[tid - o] : 0;
        __syncthreads();
        x += y; sh[tid] = x; __syncthreads();
    }
    loc[tid] = x - c;   // exclusive offset within bucket
    int node = node0 + tid;
    if (node < n) {
        rowptr[node] = base + x - c;
        invd[node] = 1.0f / (float)(c > 0 ? c : 1);
    }
    __syncthreads();
    for (int i = tid; i < cnt; i += 256) {
        u32 p = tmp[base + i];
        int ln = (p >> 16) & 255;
        int r = atomicAdd(&cnt2[ln], 1);
        srcs[base + loc[ln] + r] = (int)(p & 0xffffu);
    }
}

// ---------------- mean aggregation: one wave per node, fp8 gather ----------------
// fp8 row = 256B; 16 lanes x 16B cover a row; 4 edges per wave-load, x2 unroll
// -> 8 edges in flight. Output mean row written as bf16 to mb.
// (Kept as a standalone dispatch: fusing this into the GEMM (R3/R4) serializes gather
//  behind GEMM phases within each block and loses ~2.4x effective gather rate.)

__global__ __launch_bounds__(256) void agg_kernel(const unsigned char* __restrict__ q,
                                                  u16* __restrict__ mb,
                                                  const int* __restrict__ rowptr,
                                                  const int* __restrict__ srcs,
                                                  const float* __restrict__ invd,
                                                  int n, int npad) {
    int gw = (blockIdx.x * 256 + threadIdx.x) >> 6;  // node id
    int lane = threadIdx.x & 63;
    int qd = lane >> 4;          // edge slot within group of 4
    int fl = lane & 15;          // 16B chunk (16 feats) within the row
    if (gw >= npad) return;
    u16* orow = mb + (size_t)gw * 256;
    if (gw >= n) {
        if (lane < 16) {
            uint4 z; z.x = z.y = z.z = z.w = 0;
            uint4* p = (uint4*)(orow + lane * 16);
            p[0] = z; p[1] = z;
        }
        return;
    }
    int beg = rowptr[gw], end = rowptr[gw + 1];
    float a[16];
#pragma unroll
    for (int i = 0; i < 16; ++i) a[i] = 0.f;
    for (int base = beg; base < end; base += 64) {
        int cnt = end - base;
        if (cnt > 64) cnt = 64;
        int el = (lane < cnt) ? srcs[base + lane] : 0;
        int t = 0;
        for (; 4 * t + 8 <= cnt; t += 2) {
            int s0 = __shfl(el, 4 * t + qd);
            int s1 = __shfl(el, 4 * t + 4 + qd);
            uint4 v0 = *(const uint4*)(q + (size_t)s0 * 256 + fl * 16);
            uint4 v1 = *(const uint4*)(q + (size_t)s1 * 256 + fl * 16);
            acc16(a, v0);
            acc16(a, v1);
        }
        for (; 4 * t < cnt; ++t) {
            int ei = 4 * t + qd;
            int sj = __shfl(el, ei & 63);
            float m = (ei < cnt) ? 1.0f : 0.0f;
            uint4 v = *(const uint4*)(q + (size_t)sj * 256 + fl * 16);
            acc16m(a, v, m);
        }
    }
    // reduce the 4 quarters
#pragma unroll
    for (int i = 0; i < 16; ++i) {
        a[i] += __shfl_xor(a[i], 16);
        a[i] += __shfl_xor(a[i], 32);
    }
    if (lane < 16) {
        float sc = invd[gw];
        uint4 o0, o1;
        o0.x = pack2(a[0] * sc, a[1] * sc);
        o0.y = pack2(a[2] * sc, a[3] * sc);
        o0.z = pack2(a[4] * sc, a[5] * sc);
        o0.w = pack2(a[6] * sc, a[7] * sc);
        o1.x = pack2(a[8] * sc, a[9] * sc);
        o1.y = pack2(a[10] * sc, a[11] * sc);
        o1.z = pack2(a[12] * sc, a[13] * sc);
        o1.w = pack2(a[14] * sc, a[15] * sc);
        uint4* p = (uint4*)(orow + lane * 16);
        p[0] = o0; p[1] = o1;
    }
}

// ---------------- GEMM: 64x256 tile, BK=32; B LDS-double-buffered, A in registers ----------
// R8 (45us, best measured) staged both A and B via global_load_lds with a per-K-step
// barrier drain. R10/R11 showed the compiler will NOT hold a no-LDS register pipeline
// (VGPR 64-68, loads sunk to use). This version keeps R8's proven B-dbuf barrier loop but
// pulls A out of the drained path: each wave loads the A fragments it needs directly
// global->VGPR, prefetched ONE K-step ahead into a second named set (statically indexed
// in the fully-unrolled loop). A is 4KB/step and L2-resident; the 4x cross-wave redundancy
// costs ~4us aggregate L2 traffic. LDS drops 42->34KB; barrier drain covers only 4 B-loads.
// cur/outb NEVER alias (hb0/hb1 ping-pong in launcher — R9 race fix).
// A: rows from m (ks<8) then cur (ks>=8), both [NPAD][256] bf16 row-major.
// B: wT layer slice [n=256][k=512] bf16, k-contiguous. Wave w owns cols w*64..w*64+63.
// fin=0: store h as bf16 (outb) AND fp8 (hqb). fin=1: sigmoid, dot wo + bias -> out[row].

__global__ __launch_bounds__(256, 3) void gemm_kernel(const u16* __restrict__ mA,
                                                      const u16* __restrict__ cur,
                                                      const u16* __restrict__ wT,
                                                      u16* __restrict__ outb,
                                                      unsigned char* __restrict__ hqb,
                                                      const float* __restrict__ wo,
                                                      const float* __restrict__ bo,
                                                      float* __restrict__ out,
                                                      int n, int apply_sigmoid, int fin) {
    __shared__ u16 lB[2][256 * 32];    // [buf][row*32 + k] 16KB each
    __shared__ float lO[4][64];
    int r0 = blockIdx.x * 64;
    int tid = threadIdx.x;
    int lane = tid & 63;
    int w = tid >> 6;                  // wave id = col group (cols w*64..)
    int lrow = lane & 15, quad = lane >> 4;

    f32x4 acc[4][4] = {};

    // stage B K-step ks into LDS buffer buf (4 x global_load_lds)
    auto STAGE_B = [&](int buf, int ks) {
#pragma unroll
        for (int p = 0; p < 4; ++p) {
            int li = p * 256 + tid;        // 0..1023 -> 256 rows x 4 segs
            int row = li >> 2;
            int seg = (li & 3) << 3;
            const u16* gB = wT + (size_t)row * 512 + ks * 32 + seg;
            __builtin_amdgcn_global_load_lds(
                (__attribute__((address_space(1))) u32*)(gB),
                (__attribute__((address_space(3))) u32*)(&lB[buf][(size_t)li * 8]), 16, 0, 0);
        }
    };
    // load this wave's A fragments for K-step ks directly global->VGPR
    auto LOAD_A = [&](int ks, short8* a) {
        const u16* srcA = (ks < 8) ? mA : cur;
        int kk = (ks * 32) & 255;
        const u16* aBase = srcA + (size_t)(r0 + lrow) * 256 + kk + quad * 8;
#pragma unroll
        for (int rt = 0; rt < 4; ++rt)
            a[rt] = *(const short8*)(aBase + (size_t)rt * 16 * 256);
    };

    short8 aA[4], aB[4];
    STAGE_B(0, 0);
    LOAD_A(0, aA);
    __syncthreads();
    int buf = 0;
#pragma unroll
    for (int ks = 0; ks < 16; ++ks) {
        // prefetch next step: B into the other LDS buffer, A into the other reg set
        if (ks < 15) {
            STAGE_B(buf ^ 1, ks + 1);
            LOAD_A(ks + 1, (ks & 1) ? aA : aB);
        }
        const short8* a = (ks & 1) ? aB : aA;
        short8 b[4];
#pragma unroll
        for (int ct = 0; ct < 4; ++ct)
            b[ct] = *(const short8*)&lB[buf][(size_t)(w * 64 + ct * 16 + lrow) * 32 + quad * 8];
#pragma unroll
        for (int rt = 0; rt < 4; ++rt)
#pragma unroll
            for (int ct = 0; ct < 4; ++ct)
                acc[rt][ct] = __builtin_amdgcn_mfma_f32_16x16x32_bf16(a[rt], b[ct], acc[rt][ct], 0, 0, 0);
        __syncthreads();
        buf ^= 1;
    }

    if (!fin) {
#pragma unroll
        for (int rt = 0; rt < 4; ++rt) {
            int rbase = r0 + rt * 16 + quad * 4;
#pragma unroll
            for (int r = 0; r < 4; ++r) {
                int row = rbase + r;
                if (row < n) {
#pragma unroll
                    for (int ct = 0; ct < 4; ++ct) {
                        float v = acc[rt][ct][r];
                        if (apply_sigmoid) v = 1.0f / (1.0f + __expf(-v));
                        int col = w * 64 + ct * 16 + lrow;
                        outb[(size_t)row * 256 + col] = f2bf(v);
                        // fused fp8 emit (replaces a separate cvt_h pass)
                        u32 wq = (u32)__builtin_amdgcn_cvt_pk_fp8_f32(v, v, 0, false);
                        hqb[(size_t)row * 256 + col] = (unsigned char)(wq & 0xff);
                    }
                }
            }
        }
    } else {
        // final layer: sigmoid then dot with wo, reduce, write out
        float wv[4];
#pragma unroll
        for (int ct = 0; ct < 4; ++ct) wv[ct] = wo[w * 64 + ct * 16 + lrow];
#pragma unroll
        for (int rt = 0; rt < 4; ++rt) {
#pragma unroll
            for (int r = 0; r < 4; ++r) {
                float s = 0.f;
#pragma unroll
                for (int ct = 0; ct < 4; ++ct) {
                    float v = acc[rt][ct][r];
                    v = 1.0f / (1.0f + __expf(-v));
                    s += v * wv[ct];
                }
                // reduce across the 16 lanes (lrow bits 0..3) sharing this row
                s += __shfl_xor(s, 1);
                s += __shfl_xor(s, 2);
                s += __shfl_xor(s, 4);
                s += __shfl_xor(s, 8);
                if (lrow == 0) {
                    int rowlocal = rt * 16 + quad * 4 + r;
                    lO[w][rowlocal] = s;
                }
            }
        }
        __syncthreads();
        if (tid < 64) {
            int row = r0 + tid;
            if (row < n)
                out[row] = lO[0][tid] + lO[1][tid] + lO[2][tid] + lO[3][tid] + bo[0];
        }
    }
}

// ---------------- launch ----------------

extern "C" void kernel_launch(void* const* d_in, const int* in_sizes, int n_in,
                              void* d_out, int out_size, void* d_ws, size_t ws_size,
                              hipStream_t stream) {
    const float* x  = (const float*)d_in[0];
    const int*   ei = (const int*)d_in[1];
    const float* WA = (const float*)d_in[2];
    const float* WB = (const float*)d_in[3];
    const float* As = (const float*)d_in[4];
    const float* Bs = (const float*)d_in[5];
    const float* Wo = (const float*)d_in[6];
    const float* bo = (const float*)d_in[7];
    float* out = (float*)d_out;

    const int H = 256;
    int N = in_sizes[0] / H;
    int E = in_sizes[1] / 2;
    int L = in_sizes[4] / (H * H);
    int NPAD = (N + 127) & ~127;
    int NB = (N + 255) >> 8;           // coarse buckets (requires N <= 65536)

    char* wsp = (char*)d_ws;
    size_t off = 0;
    auto alloc = [&](size_t b) { size_t o = off; off += (b + 255) & ~(size_t)255; return o; };
    int*   rowptr = (int*)(wsp + alloc((size_t)(NPAD + 1) * 4));
    int*   ccnt   = (int*)(wsp + alloc(2048));      // ccnt[256] + cfill[256] contiguous
    int*   cfill  = ccnt + 256;
    int*   cbase  = (int*)(wsp + alloc(1032 + 256));
    float* invd   = (float*)(wsp + alloc((size_t)NPAD * 4));
    int*   srcs   = (int*)(wsp + alloc((size_t)E * 4));
    u16*   xb     = (u16*)(wsp + alloc((size_t)NPAD * H * 2));
    u16*   hb0    = (u16*)(wsp + alloc((size_t)NPAD * H * 2));  // h ping
    u16*   hb1    = (u16*)(wsp + alloc((size_t)NPAD * H * 2));  // h pong
    u16*   mb     = (u16*)(wsp + alloc((size_t)NPAD * H * 2));
    u32*   xq     = (u32*)(wsp + alloc((size_t)NPAD * H));      // fp8 x
    u32*   hq     = (u32*)(wsp + alloc((size_t)NPAD * H));      // fp8 h (gemm epilogue)
    u16*   wT     = (u16*)(wsp + alloc((size_t)(L + 1) * 512 * 256 * 2));
    // tmp (packed coarse-sorted edges) aliases mb: dead until first agg writes mb
    u32*   tmp    = (u32*)mb;

    const int* esrc = ei;
    const int* edst = ei + E;

    hipMemsetAsync(ccnt, 0, 2048, stream);

    int gridE = (E + 4095) / 4096;
    int nx = NPAD / 4;
    int nw = ((L + 1) * 512 * 256 + 255) / 256;
    prep_kernel<<<nx + nw + gridE, 256, 0, stream>>>(x, xb, xq, N, nx,
                                                     WA, WB, As, Bs, wT, L + 1, nw,
                                                     edst, ccnt, E, NB);
    scan_coarse_kernel<<<1, 256, 0, stream>>>(ccnt, cbase, rowptr, NB, N, E);
    passA_kernel<<<gridE, 256, 0, stream>>>(esrc, edst, cbase, cfill, tmp, E, NB);
    passB_kernel<<<NB, 256, 0, stream>>>(tmp, cbase, rowptr, invd, srcs, N);

    const u16* cur = xb;
    const unsigned char* curq = (const unsigned char*)xq;
    u16* hnext = hb0;
    for (int s = 0; s <= L; ++s) {
        int fin = (s == L) ? 1 : 0;
        agg_kernel<<<NPAD / 4, 256, 0, stream>>>(curq, mb, rowptr, srcs, invd, N, NPAD);
        gemm_kernel<<<NPAD / 64, 256, 0, stream>>>(mb, cur, wT + (size_t)s * 512 * 256, hnext,
                                                   (unsigned char*)hq, Wo, bo, out, N,
                                                   s > 0 ? 1 : 0, fin);
        if (!fin) {
            cur = hnext;
            curq = (const unsigned char*)hq;
            hnext = (hnext == hb0) ? hb1 : hb0;
        }
    }
}

// Round 13
// 348.706 us; speedup vs baseline: 1.2888x; 1.1035x over previous
//
#include <hip/hip_runtime.h>

typedef unsigned short u16;
typedef unsigned int u32;
typedef __attribute__((ext_vector_type(8))) short short8;
typedef __attribute__((ext_vector_type(4))) float f32x4;
typedef __attribute__((ext_vector_type(2))) float f32x2;

__device__ __forceinline__ float bf2f(u16 u) {
    return __uint_as_float(((u32)u) << 16);
}
__device__ __forceinline__ u16 f2bf(float f) {
    u32 u = __float_as_uint(f);
    u += 0x7fff + ((u >> 16) & 1);   // round-to-nearest-even
    return (u16)(u >> 16);
}
__device__ __forceinline__ u32 pack2(float a, float b) {
    return (u32)f2bf(a) | ((u32)f2bf(b) << 16);
}
// pack 4 floats -> 4 fp8 e4m3 in one u32
__device__ __forceinline__ u32 pk_fp8x4(float f0, float f1, float f2, float f3) {
    int w = __builtin_amdgcn_cvt_pk_fp8_f32(f0, f1, 0, false);
    w = __builtin_amdgcn_cvt_pk_fp8_f32(f2, f3, w, true);
    return (u32)w;
}
// accumulate 4 fp8 (one u32) into a[0..3]
__device__ __forceinline__ void acc4(float* a, u32 w) {
    f32x2 lo = __builtin_amdgcn_cvt_pk_f32_fp8((int)w, false);
    f32x2 hi = __builtin_amdgcn_cvt_pk_f32_fp8((int)w, true);
    a[0] += lo.x; a[1] += lo.y; a[2] += hi.x; a[3] += hi.y;
}
__device__ __forceinline__ void acc4m(float* a, u32 w, float m) {
    f32x2 lo = __builtin_amdgcn_cvt_pk_f32_fp8((int)w, false);
    f32x2 hi = __builtin_amdgcn_cvt_pk_f32_fp8((int)w, true);
    a[0] += m * lo.x; a[1] += m * lo.y; a[2] += m * hi.x; a[3] += m * hi.y;
}
__device__ __forceinline__ void acc16(float* a, uint4 v) {
    acc4(a + 0, v.x); acc4(a + 4, v.y); acc4(a + 8, v.z); acc4(a + 12, v.w);
}
__device__ __forceinline__ void acc16m(float* a, uint4 v, float m) {
    acc4m(a + 0, v.x, m); acc4m(a + 4, v.y, m); acc4m(a + 8, v.z, m); acc4m(a + 12, v.w, m);
}

// ---------------- merged prep: cvt_x | cvt_w | hist (branch on blockIdx range) ----------------

__global__ __launch_bounds__(256) void prep_kernel(const float* __restrict__ x,
                                                   u16* __restrict__ xb, u32* __restrict__ xq,
                                                   int n, int nx,
                                                   const float* __restrict__ WA,
                                                   const float* __restrict__ WB,
                                                   const float* __restrict__ As,
                                                   const float* __restrict__ Bs,
                                                   u16* __restrict__ wT, int nlayers, int nw,
                                                   const int* __restrict__ dst,
                                                   int* __restrict__ ccnt, int e, int nb) {
    __shared__ int h[256];
    int b = blockIdx.x;
    int tid = threadIdx.x;
    if (b < nx) {
        // ---- cvt_x ----
        int i = b * 256 + tid;                    // group of 4 elements
        int row = i >> 6;                         // 64 groups per 256-wide row
        ushort4 o;
        u32 q;
        if (row < n) {
            float4 v = ((const float4*)x)[i];
            o.x = f2bf(v.x); o.y = f2bf(v.y); o.z = f2bf(v.z); o.w = f2bf(v.w);
            q = pk_fp8x4(v.x, v.y, v.z, v.w);
        } else {
            o.x = o.y = o.z = o.w = 0;
            q = 0;
        }
        ((ushort4*)xb)[i] = o;
        xq[i] = q;
    } else if (b < nx + nw) {
        // ---- cvt_w ----
        int i = (b - nx) * 256 + tid;
        const int per = 256 * 512;
        if (i >= nlayers * per) return;
        int l = i / per;
        int rem = i - l * per;
        int nn = rem >> 9;
        int k = rem & 511;
        const float* Aw = (l == 0) ? WA : As + (size_t)(l - 1) * 65536;
        const float* Bw = (l == 0) ? WB : Bs + (size_t)(l - 1) * 65536;
        float v = (k < 256) ? Aw[(size_t)k * 256 + nn] : Bw[(size_t)(k - 256) * 256 + nn];
        wT[i] = f2bf(v);
    } else {
        // ---- hist ----
        h[tid] = 0;
        __syncthreads();
        int e0 = (b - nx - nw) * 4096;
#pragma unroll
        for (int j = 0; j < 16; ++j) {
            int i = e0 + j * 256 + tid;
            if (i < e) atomicAdd(&h[dst[i] >> 8], 1);
        }
        __syncthreads();
        if (tid < nb) {
            int v = h[tid];
            if (v) atomicAdd(&ccnt[tid], v);
        }
    }
}

// ---------------- CSR build: two-level counting sort ----------------
// Requires N <= 65536 so an edge packs into u32 as (dst<<16)|src.
// Coarse bucket b covers nodes [b*256, b*256+256).

__global__ __launch_bounds__(256) void scan_coarse_kernel(const int* __restrict__ ccnt,
                                                          int* __restrict__ cbase,
                                                          int* __restrict__ rowptr,
                                                          int nb, int n, int e) {
    __shared__ int sh[256];
    int t = threadIdx.x;
    int v = (t < nb) ? ccnt[t] : 0;
    int x = v;
    sh[t] = x; __syncthreads();
    for (int o = 1; o < 256; o <<= 1) {
        int y = (t >= o) ? sh[t - o] : 0;
        __syncthreads();
        x += y; sh[t] = x; __syncthreads();
    }
    if (t < nb) cbase[t] = x - v;
    if (t == 0) { cbase[nb] = e; rowptr[n] = e; }
}

__global__ __launch_bounds__(256) void passA_kernel(const int* __restrict__ src,
                                                    const int* __restrict__ dst,
                                                    const int* __restrict__ cbase,
                                                    int* __restrict__ cfill,
                                                    u32* __restrict__ tmp, int e, int nb) {
    __shared__ int ph[256], pb[256], pr[256], cb[256];
    __shared__ u32 ed[4096];
    int tid = threadIdx.x;
    ph[tid] = 0; pr[tid] = 0;
    cb[tid] = (tid < nb) ? cbase[tid] : 0;
    __syncthreads();
    int e0 = blockIdx.x * 4096;
#pragma unroll
    for (int j = 0; j < 16; ++j) {
        int i = e0 + j * 256 + tid;
        u32 p = 0xFFFFFFFFu;
        if (i < e) {
            int d = dst[i];
            p = ((u32)d << 16) | (u32)src[i];
            atomicAdd(&ph[d >> 8], 1);
        }
        ed[j * 256 + tid] = p;
    }
    __syncthreads();
    pb[tid] = (tid < nb && ph[tid]) ? atomicAdd(&cfill[tid], ph[tid]) : 0;
    __syncthreads();
#pragma unroll
    for (int j = 0; j < 16; ++j) {
        u32 p = ed[j * 256 + tid];
        if (p != 0xFFFFFFFFu) {
            int bk = p >> 24;
            int r = atomicAdd(&pr[bk], 1);
            tmp[cb[bk] + pb[bk] + r] = p;
        }
    }
}

__global__ __launch_bounds__(256) void passB_kernel(const u32* __restrict__ tmp,
                                                    const int* __restrict__ cbase,
                                                    int* __restrict__ rowptr,
                                                    float* __restrict__ invd,
                                                    int* __restrict__ srcs, int n) {
    __shared__ int h[256], loc[256], cnt2[256], sh[256];
    int b = blockIdx.x;
    int tid = threadIdx.x;
    int base = cbase[b];
    int cnt = cbase[b + 1] - base;
    int node0 = b << 8;
    h[tid] = 0; cnt2[tid] = 0;
    __syncthreads();
    for (int i = tid; i < cnt; i += 256)
        atomicAdd(&h[(tmp[base + i] >> 16) & 255], 1);
    __syncthreads();
    int c = h[tid];
    int x = c;
    sh[tid] = x; __syncthreads();
    for (int o = 1; o < 256; o <<= 1) {
        int y = (tid >= o) ? sh[tid - o] : 0;
        __syncthreads();
        x += y; sh[tid] = x; __syncthreads();
    }
    loc[tid] = x - c;   // exclusive offset within bucket
    int node = node0 + tid;
    if (node < n) {
        rowptr[node] = base + x - c;
        invd[node] = 1.0f / (float)(c > 0 ? c : 1);
    }
    __syncthreads();
    for (int i = tid; i < cnt; i += 256) {
        u32 p = tmp[base + i];
        int ln = (p >> 16) & 255;
        int r = atomicAdd(&cnt2[ln], 1);
        srcs[base + loc[ln] + r] = (int)(p & 0xffffu);
    }
}

// ---------------- mean aggregation: one wave per node, fp8 gather ----------------
// fp8 row = 256B; 16 lanes x 16B cover a row; 4 edges per wave-load, x2 unroll
// -> 8 edges in flight. Output mean row written as bf16 to mb.
// (Kept as a standalone dispatch: fusing this into the GEMM (R3/R4) serializes gather
//  behind GEMM phases within each block and loses ~2.4x effective gather rate.)

__global__ __launch_bounds__(256) void agg_kernel(const unsigned char* __restrict__ q,
                                                  u16* __restrict__ mb,
                                                  const int* __restrict__ rowptr,
                                                  const int* __restrict__ srcs,
                                                  const float* __restrict__ invd,
                                                  int n, int npad) {
    int gw = (blockIdx.x * 256 + threadIdx.x) >> 6;  // node id
    int lane = threadIdx.x & 63;
    int qd = lane >> 4;          // edge slot within group of 4
    int fl = lane & 15;          // 16B chunk (16 feats) within the row
    if (gw >= npad) return;
    u16* orow = mb + (size_t)gw * 256;
    if (gw >= n) {
        if (lane < 16) {
            uint4 z; z.x = z.y = z.z = z.w = 0;
            uint4* p = (uint4*)(orow + lane * 16);
            p[0] = z; p[1] = z;
        }
        return;
    }
    int beg = rowptr[gw], end = rowptr[gw + 1];
    float a[16];
#pragma unroll
    for (int i = 0; i < 16; ++i) a[i] = 0.f;
    for (int base = beg; base < end; base += 64) {
        int cnt = end - base;
        if (cnt > 64) cnt = 64;
        int el = (lane < cnt) ? srcs[base + lane] : 0;
        int t = 0;
        for (; 4 * t + 8 <= cnt; t += 2) {
            int s0 = __shfl(el, 4 * t + qd);
            int s1 = __shfl(el, 4 * t + 4 + qd);
            uint4 v0 = *(const uint4*)(q + (size_t)s0 * 256 + fl * 16);
            uint4 v1 = *(const uint4*)(q + (size_t)s1 * 256 + fl * 16);
            acc16(a, v0);
            acc16(a, v1);
        }
        for (; 4 * t < cnt; ++t) {
            int ei = 4 * t + qd;
            int sj = __shfl(el, ei & 63);
            float m = (ei < cnt) ? 1.0f : 0.0f;
            uint4 v = *(const uint4*)(q + (size_t)sj * 256 + fl * 16);
            acc16m(a, v, m);
        }
    }
    // reduce the 4 quarters
#pragma unroll
    for (int i = 0; i < 16; ++i) {
        a[i] += __shfl_xor(a[i], 16);
        a[i] += __shfl_xor(a[i], 32);
    }
    if (lane < 16) {
        float sc = invd[gw];
        uint4 o0, o1;
        o0.x = pack2(a[0] * sc, a[1] * sc);
        o0.y = pack2(a[2] * sc, a[3] * sc);
        o0.z = pack2(a[4] * sc, a[5] * sc);
        o0.w = pack2(a[6] * sc, a[7] * sc);
        o1.x = pack2(a[8] * sc, a[9] * sc);
        o1.y = pack2(a[10] * sc, a[11] * sc);
        o1.z = pack2(a[12] * sc, a[13] * sc);
        o1.w = pack2(a[14] * sc, a[15] * sc);
        uint4* p = (uint4*)(orow + lane * 16);
        p[0] = o0; p[1] = o1;
    }
}

// ---------------- GEMM: 64x256 tile, BK=32 LDS-dbuf (R8) + COUNTED-VMCNT barriers (T4) ----
// R8 (45us best) drains vmcnt(0) at every __syncthreads — the prefetch it just issued is
// drained too, so it never overlaps. R10-R12 proved the compiler won't register-pipeline.
// This keeps R8's exact data path (A+B via global_load_lds, BK=32 double-buffer) and only
// changes the SYNC: raw s_barrier (asm, "memory" clobber) + counted s_waitcnt vmcnt(5):
// per iter each wave issues 5 gload_lds for the NEXT buffer, then waits vmcnt(5) — vmem
// completes in order, so this waits exactly the 5 OLDER loads (current buffer) while the
// prefetch stays in flight across both barriers. Trailing lgkmcnt(0)+barrier protects the
// buffer being overwritten next iter. (8-phase template's minimum 2-phase pattern.)
// cur/outb never alias (hb0/hb1 ping-pong in launcher).
// A: rows from m (ks<8) then cur (ks>=8), both [NPAD][256] bf16 row-major.
// B: wT layer slice [n=256][k=512] bf16, k-contiguous. Wave w owns cols w*64..w*64+63.
// fin=0: store h as bf16 (outb) AND fp8 (hqb). fin=1: sigmoid, dot wo + bias -> out[row].

__global__ __launch_bounds__(256, 4) void gemm_kernel(const u16* __restrict__ mA,
                                                      const u16* __restrict__ cur,
                                                      const u16* __restrict__ wT,
                                                      u16* __restrict__ outb,
                                                      unsigned char* __restrict__ hqb,
                                                      const float* __restrict__ wo,
                                                      const float* __restrict__ bo,
                                                      float* __restrict__ out,
                                                      int n, int apply_sigmoid, int fin) {
    __shared__ u16 lA[2][64 * 32];     // [buf][row*32 + k]  4KB each
    __shared__ u16 lB[2][256 * 32];    // [buf][row*32 + k] 16KB each
    __shared__ float lO[4][64];
    int r0 = blockIdx.x * 64;
    int tid = threadIdx.x;
    int lane = tid & 63;
    int w = tid >> 6;                  // wave id = col group (cols w*64..)
    int lrow = lane & 15, quad = lane >> 4;

    f32x4 acc[4][4] = {};

    // stage 32-wide K-step ks into LDS buffer buf (5 x global_load_lds per thread)
    auto STAGE = [&](int buf, int ks) {
        const u16* srcA = (ks < 8) ? mA : cur;
        int kk = (ks * 32) & 255;
        {
            int li = tid;                  // 0..255 -> 64 rows x 4 segs
            int row = li >> 2;
            int seg = (li & 3) << 3;
            const u16* gA = srcA + (size_t)(r0 + row) * 256 + kk + seg;
            __builtin_amdgcn_global_load_lds(
                (__attribute__((address_space(1))) u32*)(gA),
                (__attribute__((address_space(3))) u32*)(&lA[buf][(size_t)li * 8]), 16, 0, 0);
        }
#pragma unroll
        for (int p = 0; p < 4; ++p) {
            int li = p * 256 + tid;        // 0..1023 -> 256 rows x 4 segs
            int row = li >> 2;
            int seg = (li & 3) << 3;
            const u16* gB = wT + (size_t)row * 512 + ks * 32 + seg;
            __builtin_amdgcn_global_load_lds(
                (__attribute__((address_space(1))) u32*)(gB),
                (__attribute__((address_space(3))) u32*)(&lB[buf][(size_t)li * 8]), 16, 0, 0);
        }
    };

    STAGE(0, 0);
    int buf = 0;
#pragma unroll
    for (int ks = 0; ks < 16; ++ks) {
        if (ks < 15) {
            STAGE(buf ^ 1, ks + 1);        // 5 prefetch loads now in flight
            // wait for the 5 OLDER loads (current buf); keep prefetch outstanding
            asm volatile("s_waitcnt vmcnt(5)" ::: "memory");
        } else {
            asm volatile("s_waitcnt vmcnt(0)" ::: "memory");
        }
        __builtin_amdgcn_sched_barrier(0);
        asm volatile("s_barrier" ::: "memory");   // all waves' buf data landed

        short8 a[4], b[4];
#pragma unroll
        for (int rt = 0; rt < 4; ++rt)
            a[rt] = *(const short8*)&lA[buf][(size_t)(rt * 16 + lrow) * 32 + quad * 8];
#pragma unroll
        for (int ct = 0; ct < 4; ++ct)
            b[ct] = *(const short8*)&lB[buf][(size_t)(w * 64 + ct * 16 + lrow) * 32 + quad * 8];
#pragma unroll
        for (int rt = 0; rt < 4; ++rt)
#pragma unroll
            for (int ct = 0; ct < 4; ++ct)
                acc[rt][ct] = __builtin_amdgcn_mfma_f32_16x16x32_bf16(a[rt], b[ct], acc[rt][ct], 0, 0, 0);

        asm volatile("s_waitcnt lgkmcnt(0)" ::: "memory");  // my ds_reads of buf done
        __builtin_amdgcn_sched_barrier(0);
        asm volatile("s_barrier" ::: "memory");   // everyone done reading buf -> safe to overwrite
        buf ^= 1;
    }

    if (!fin) {
#pragma unroll
        for (int rt = 0; rt < 4; ++rt) {
            int rbase = r0 + rt * 16 + quad * 4;
#pragma unroll
            for (int r = 0; r < 4; ++r) {
                int row = rbase + r;
                if (row < n) {
#pragma unroll
                    for (int ct = 0; ct < 4; ++ct) {
                        float v = acc[rt][ct][r];
                        if (apply_sigmoid) v = 1.0f / (1.0f + __expf(-v));
                        int col = w * 64 + ct * 16 + lrow;
                        outb[(size_t)row * 256 + col] = f2bf(v);
                        // fused fp8 emit (replaces a separate cvt_h pass)
                        u32 wq = (u32)__builtin_amdgcn_cvt_pk_fp8_f32(v, v, 0, false);
                        hqb[(size_t)row * 256 + col] = (unsigned char)(wq & 0xff);
                    }
                }
            }
        }
    } else {
        // final layer: sigmoid then dot with wo, reduce, write out
        float wv[4];
#pragma unroll
        for (int ct = 0; ct < 4; ++ct) wv[ct] = wo[w * 64 + ct * 16 + lrow];
#pragma unroll
        for (int rt = 0; rt < 4; ++rt) {
#pragma unroll
            for (int r = 0; r < 4; ++r) {
                float s = 0.f;
#pragma unroll
                for (int ct = 0; ct < 4; ++ct) {
                    float v = acc[rt][ct][r];
                    v = 1.0f / (1.0f + __expf(-v));
                    s += v * wv[ct];
                }
                // reduce across the 16 lanes (lrow bits 0..3) sharing this row
                s += __shfl_xor(s, 1);
                s += __shfl_xor(s, 2);
                s += __shfl_xor(s, 4);
                s += __shfl_xor(s, 8);
                if (lrow == 0) {
                    int rowlocal = rt * 16 + quad * 4 + r;
                    lO[w][rowlocal] = s;
                }
            }
        }
        __syncthreads();
        if (tid < 64) {
            int row = r0 + tid;
            if (row < n)
                out[row] = lO[0][tid] + lO[1][tid] + lO[2][tid] + lO[3][tid] + bo[0];
        }
    }
}

// ---------------- launch ----------------

extern "C" void kernel_launch(void* const* d_in, const int* in_sizes, int n_in,
                              void* d_out, int out_size, void* d_ws, size_t ws_size,
                              hipStream_t stream) {
    const float* x  = (const float*)d_in[0];
    const int*   ei = (const int*)d_in[1];
    const float* WA = (const float*)d_in[2];
    const float* WB = (const float*)d_in[3];
    const float* As = (const float*)d_in[4];
    const float* Bs = (const float*)d_in[5];
    const float* Wo = (const float*)d_in[6];
    const float* bo = (const float*)d_in[7];
    float* out = (float*)d_out;

    const int H = 256;
    int N = in_sizes[0] / H;
    int E = in_sizes[1] / 2;
    int L = in_sizes[4] / (H * H);
    int NPAD = (N + 127) & ~127;
    int NB = (N + 255) >> 8;           // coarse buckets (requires N <= 65536)

    char* wsp = (char*)d_ws;
    size_t off = 0;
    auto alloc = [&](size_t b) { size_t o = off; off += (b + 255) & ~(size_t)255; return o; };
    int*   rowptr = (int*)(wsp + alloc((size_t)(NPAD + 1) * 4));
    int*   ccnt   = (int*)(wsp + alloc(2048));      // ccnt[256] + cfill[256] contiguous
    int*   cfill  = ccnt + 256;
    int*   cbase  = (int*)(wsp + alloc(1032 + 256));
    float* invd   = (float*)(wsp + alloc((size_t)NPAD * 4));
    int*   srcs   = (int*)(wsp + alloc((size_t)E * 4));
    u16*   xb     = (u16*)(wsp + alloc((size_t)NPAD * H * 2));
    u16*   hb0    = (u16*)(wsp + alloc((size_t)NPAD * H * 2));  // h ping
    u16*   hb1    = (u16*)(wsp + alloc((size_t)NPAD * H * 2));  // h pong
    u16*   mb     = (u16*)(wsp + alloc((size_t)NPAD * H * 2));
    u32*   xq     = (u32*)(wsp + alloc((size_t)NPAD * H));      // fp8 x
    u32*   hq     = (u32*)(wsp + alloc((size_t)NPAD * H));      // fp8 h (gemm epilogue)
    u16*   wT     = (u16*)(wsp + alloc((size_t)(L + 1) * 512 * 256 * 2));
    // tmp (packed coarse-sorted edges) aliases mb: dead until first agg writes mb
    u32*   tmp    = (u32*)mb;

    const int* esrc = ei;
    const int* edst = ei + E;

    hipMemsetAsync(ccnt, 0, 2048, stream);

    int gridE = (E + 4095) / 4096;
    int nx = NPAD / 4;
    int nw = ((L + 1) * 512 * 256 + 255) / 256;
    prep_kernel<<<nx + nw + gridE, 256, 0, stream>>>(x, xb, xq, N, nx,
                                                     WA, WB, As, Bs, wT, L + 1, nw,
                                                     edst, ccnt, E, NB);
    scan_coarse_kernel<<<1, 256, 0, stream>>>(ccnt, cbase, rowptr, NB, N, E);
    passA_kernel<<<gridE, 256, 0, stream>>>(esrc, edst, cbase, cfill, tmp, E, NB);
    passB_kernel<<<NB, 256, 0, stream>>>(tmp, cbase, rowptr, invd, srcs, N);

    const u16* cur = xb;
    const unsigned char* curq = (const unsigned char*)xq;
    u16* hnext = hb0;
    for (int s = 0; s <= L; ++s) {
        int fin = (s == L) ? 1 : 0;
        agg_kernel<<<NPAD / 4, 256, 0, stream>>>(curq, mb, rowptr, srcs, invd, N, NPAD);
        gemm_kernel<<<NPAD / 64, 256, 0, stream>>>(mb, cur, wT + (size_t)s * 512 * 256, hnext,
                                                   (unsigned char*)hq, Wo, bo, out, N,
                                                   s > 0 ? 1 : 0, fin);
        if (!fin) {
            cur = hnext;
            curq = (const unsigned char*)hq;
            hnext = (hnext == hb0) ? hb1 : hb0;
        }
    }
}

// Round 14
// 344.668 us; speedup vs baseline: 1.3039x; 1.0117x over previous
//
#include <hip/hip_runtime.h>

typedef unsigned short u16;
typedef unsigned int u32;
typedef __attribute__((ext_vector_type(8))) short short8;
typedef __attribute__((ext_vector_type(4))) float f32x4;
typedef __attribute__((ext_vector_type(2))) float f32x2;

__device__ __forceinline__ float bf2f(u16 u) {
    return __uint_as_float(((u32)u) << 16);
}
__device__ __forceinline__ u16 f2bf(float f) {
    u32 u = __float_as_uint(f);
    u += 0x7fff + ((u >> 16) & 1);   // round-to-nearest-even
    return (u16)(u >> 16);
}
__device__ __forceinline__ u32 pack2(float a, float b) {
    return (u32)f2bf(a) | ((u32)f2bf(b) << 16);
}
// pack 4 floats -> 4 fp8 e4m3 in one u32
__device__ __forceinline__ u32 pk_fp8x4(float f0, float f1, float f2, float f3) {
    int w = __builtin_amdgcn_cvt_pk_fp8_f32(f0, f1, 0, false);
    w = __builtin_amdgcn_cvt_pk_fp8_f32(f2, f3, w, true);
    return (u32)w;
}
// accumulate 4 fp8 (one u32) into a[0..3]
__device__ __forceinline__ void acc4(float* a, u32 w) {
    f32x2 lo = __builtin_amdgcn_cvt_pk_f32_fp8((int)w, false);
    f32x2 hi = __builtin_amdgcn_cvt_pk_f32_fp8((int)w, true);
    a[0] += lo.x; a[1] += lo.y; a[2] += hi.x; a[3] += hi.y;
}
__device__ __forceinline__ void acc4m(float* a, u32 w, float m) {
    f32x2 lo = __builtin_amdgcn_cvt_pk_f32_fp8((int)w, false);
    f32x2 hi = __builtin_amdgcn_cvt_pk_f32_fp8((int)w, true);
    a[0] += m * lo.x; a[1] += m * lo.y; a[2] += m * hi.x; a[3] += m * hi.y;
}
__device__ __forceinline__ void acc16(float* a, uint4 v) {
    acc4(a + 0, v.x); acc4(a + 4, v.y); acc4(a + 8, v.z); acc4(a + 12, v.w);
}
__device__ __forceinline__ void acc16m(float* a, uint4 v, float m) {
    acc4m(a + 0, v.x, m); acc4m(a + 4, v.y, m); acc4m(a + 8, v.z, m); acc4m(a + 12, v.w, m);
}

// ---------------- merged prep: cvt_x | cvt_w | hist (branch on blockIdx range) ----------------

__global__ __launch_bounds__(256) void prep_kernel(const float* __restrict__ x,
                                                   u16* __restrict__ xb, u32* __restrict__ xq,
                                                   int n, int nx,
                                                   const float* __restrict__ WA,
                                                   const float* __restrict__ WB,
                                                   const float* __restrict__ As,
                                                   const float* __restrict__ Bs,
                                                   u16* __restrict__ wT, int nlayers, int nw,
                                                   const int* __restrict__ dst,
                                                   int* __restrict__ ccnt, int e, int nb) {
    __shared__ int h[256];
    int b = blockIdx.x;
    int tid = threadIdx.x;
    if (b < nx) {
        // ---- cvt_x ----
        int i = b * 256 + tid;                    // group of 4 elements
        int row = i >> 6;                         // 64 groups per 256-wide row
        ushort4 o;
        u32 q;
        if (row < n) {
            float4 v = ((const float4*)x)[i];
            o.x = f2bf(v.x); o.y = f2bf(v.y); o.z = f2bf(v.z); o.w = f2bf(v.w);
            q = pk_fp8x4(v.x, v.y, v.z, v.w);
        } else {
            o.x = o.y = o.z = o.w = 0;
            q = 0;
        }
        ((ushort4*)xb)[i] = o;
        xq[i] = q;
    } else if (b < nx + nw) {
        // ---- cvt_w ----
        int i = (b - nx) * 256 + tid;
        const int per = 256 * 512;
        if (i >= nlayers * per) return;
        int l = i / per;
        int rem = i - l * per;
        int nn = rem >> 9;
        int k = rem & 511;
        const float* Aw = (l == 0) ? WA : As + (size_t)(l - 1) * 65536;
        const float* Bw = (l == 0) ? WB : Bs + (size_t)(l - 1) * 65536;
        float v = (k < 256) ? Aw[(size_t)k * 256 + nn] : Bw[(size_t)(k - 256) * 256 + nn];
        wT[i] = f2bf(v);
    } else {
        // ---- hist ----
        h[tid] = 0;
        __syncthreads();
        int e0 = (b - nx - nw) * 4096;
#pragma unroll
        for (int j = 0; j < 16; ++j) {
            int i = e0 + j * 256 + tid;
            if (i < e) atomicAdd(&h[dst[i] >> 8], 1);
        }
        __syncthreads();
        if (tid < nb) {
            int v = h[tid];
            if (v) atomicAdd(&ccnt[tid], v);
        }
    }
}

// ---------------- CSR build: two-level counting sort ----------------
// Requires N <= 65536 so an edge packs into u32 as (dst<<16)|src.
// Coarse bucket b covers nodes [b*256, b*256+256).

__global__ __launch_bounds__(256) void scan_coarse_kernel(const int* __restrict__ ccnt,
                                                          int* __restrict__ cbase,
                                                          int* __restrict__ rowptr,
                                                          int nb, int n, int e) {
    __shared__ int sh[256];
    int t = threadIdx.x;
    int v = (t < nb) ? ccnt[t] : 0;
    int x = v;
    sh[t] = x; __syncthreads();
    for (int o = 1; o < 256; o <<= 1) {
        int y = (t >= o) ? sh[t - o] : 0;
        __syncthreads();
        x += y; sh[t] = x; __syncthreads();
    }
    if (t < nb) cbase[t] = x - v;
    if (t == 0) { cbase[nb] = e; rowptr[n] = e; }
}

__global__ __launch_bounds__(256) void passA_kernel(const int* __restrict__ src,
                                                    const int* __restrict__ dst,
                                                    const int* __restrict__ cbase,
                                                    int* __restrict__ cfill,
                                                    u32* __restrict__ tmp, int e, int nb) {
    __shared__ int ph[256], pb[256], pr[256], cb[256];
    __shared__ u32 ed[4096];
    int tid = threadIdx.x;
    ph[tid] = 0; pr[tid] = 0;
    cb[tid] = (tid < nb) ? cbase[tid] : 0;
    __syncthreads();
    int e0 = blockIdx.x * 4096;
#pragma unroll
    for (int j = 0; j < 16; ++j) {
        int i = e0 + j * 256 + tid;
        u32 p = 0xFFFFFFFFu;
        if (i < e) {
            int d = dst[i];
            p = ((u32)d << 16) | (u32)src[i];
            atomicAdd(&ph[d >> 8], 1);
        }
        ed[j * 256 + tid] = p;
    }
    __syncthreads();
    pb[tid] = (tid < nb && ph[tid]) ? atomicAdd(&cfill[tid], ph[tid]) : 0;
    __syncthreads();
#pragma unroll
    for (int j = 0; j < 16; ++j) {
        u32 p = ed[j * 256 + tid];
        if (p != 0xFFFFFFFFu) {
            int bk = p >> 24;
            int r = atomicAdd(&pr[bk], 1);
            tmp[cb[bk] + pb[bk] + r] = p;
        }
    }
}

__global__ __launch_bounds__(256) void passB_kernel(const u32* __restrict__ tmp,
                                                    const int* __restrict__ cbase,
                                                    int* __restrict__ rowptr,
                                                    float* __restrict__ invd,
                                                    int* __restrict__ srcs, int n) {
    __shared__ int h[256], loc[256], cnt2[256], sh[256];
    int b = blockIdx.x;
    int tid = threadIdx.x;
    int base = cbase[b];
    int cnt = cbase[b + 1] - base;
    int node0 = b << 8;
    h[tid] = 0; cnt2[tid] = 0;
    __syncthreads();
    for (int i = tid; i < cnt; i += 256)
        atomicAdd(&h[(tmp[base + i] >> 16) & 255], 1);
    __syncthreads();
    int c = h[tid];
    int x = c;
    sh[tid] = x; __syncthreads();
    for (int o = 1; o < 256; o <<= 1) {
        int y = (tid >= o) ? sh[tid - o] : 0;
        __syncthreads();
        x += y; sh[tid] = x; __syncthreads();
    }
    loc[tid] = x - c;   // exclusive offset within bucket
    int node = node0 + tid;
    if (node < n) {
        rowptr[node] = base + x - c;
        invd[node] = 1.0f / (float)(c > 0 ? c : 1);
    }
    __syncthreads();
    for (int i = tid; i < cnt; i += 256) {
        u32 p = tmp[base + i];
        int ln = (p >> 16) & 255;
        int r = atomicAdd(&cnt2[ln], 1);
        srcs[base + loc[ln] + r] = (int)(p & 0xffffu);
    }
}

// ---------------- mean aggregation: one wave per node, fp8 gather ----------------
// fp8 row = 256B; 16 lanes x 16B cover a row; 4 edges per wave-load, x2 unroll
// -> 8 edges in flight. Output mean row written as bf16 to mb.
// (Kept as a standalone dispatch: fusing this into the GEMM (R3/R4) serializes gather
//  behind GEMM phases within each block and loses ~2.4x effective gather rate.)

__global__ __launch_bounds__(256) void agg_kernel(const unsigned char* __restrict__ q,
                                                  u16* __restrict__ mb,
                                                  const int* __restrict__ rowptr,
                                                  const int* __restrict__ srcs,
                                                  const float* __restrict__ invd,
                                                  int n, int npad) {
    int gw = (blockIdx.x * 256 + threadIdx.x) >> 6;  // node id
    int lane = threadIdx.x & 63;
    int qd = lane >> 4;          // edge slot within group of 4
    int fl = lane & 15;          // 16B chunk (16 feats) within the row
    if (gw >= npad) return;
    u16* orow = mb + (size_t)gw * 256;
    if (gw >= n) {
        if (lane < 16) {
            uint4 z; z.x = z.y = z.z = z.w = 0;
            uint4* p = (uint4*)(orow + lane * 16);
            p[0] = z; p[1] = z;
        }
        return;
    }
    int beg = rowptr[gw], end = rowptr[gw + 1];
    float a[16];
#pragma unroll
    for (int i = 0; i < 16; ++i) a[i] = 0.f;
    for (int base = beg; base < end; base += 64) {
        int cnt = end - base;
        if (cnt > 64) cnt = 64;
        int el = (lane < cnt) ? srcs[base + lane] : 0;
        int t = 0;
        for (; 4 * t + 8 <= cnt; t += 2) {
            int s0 = __shfl(el, 4 * t + qd);
            int s1 = __shfl(el, 4 * t + 4 + qd);
            uint4 v0 = *(const uint4*)(q + (size_t)s0 * 256 + fl * 16);
            uint4 v1 = *(const uint4*)(q + (size_t)s1 * 256 + fl * 16);
            acc16(a, v0);
            acc16(a, v1);
        }
        for (; 4 * t < cnt; ++t) {
            int ei = 4 * t + qd;
            int sj = __shfl(el, ei & 63);
            float m = (ei < cnt) ? 1.0f : 0.0f;
            uint4 v = *(const uint4*)(q + (size_t)sj * 256 + fl * 16);
            acc16m(a, v, m);
        }
    }
    // reduce the 4 quarters
#pragma unroll
    for (int i = 0; i < 16; ++i) {
        a[i] += __shfl_xor(a[i], 16);
        a[i] += __shfl_xor(a[i], 32);
    }
    if (lane < 16) {
        float sc = invd[gw];
        uint4 o0, o1;
        o0.x = pack2(a[0] * sc, a[1] * sc);
        o0.y = pack2(a[2] * sc, a[3] * sc);
        o0.z = pack2(a[4] * sc, a[5] * sc);
        o0.w = pack2(a[6] * sc, a[7] * sc);
        o1.x = pack2(a[8] * sc, a[9] * sc);
        o1.y = pack2(a[10] * sc, a[11] * sc);
        o1.z = pack2(a[12] * sc, a[13] * sc);
        o1.w = pack2(a[14] * sc, a[15] * sc);
        uint4* p = (uint4*)(orow + lane * 16);
        p[0] = o0; p[1] = o1;
    }
}

// ---------------- GEMM: 64x256 tile, BK=32 LDS-dbuf + counted vmcnt + 16B XOR SWIZZLE ----
// R13 post-mortem: counted vmcnt didn't move the 45us plateau; the real stall is
// SQ_LDS_BANK_CONFLICT = 1.6M/dispatch ~ 4 conflict-cycles per ds_read_b128. In the
// [row][32] layout a lane reads byte row*64 + quad*16; within an 8-lane scheduling group
// (quad fixed, lrow 0-7) even lrows all start at banks 0-3, odd at 16-19 -> 4-way
// conflict on EVERY fragment read (present in R5/R7/R8/R12/R13 -> sync-invariant 45us).
// FIX (T2 + rule 21): store logical seg q of row r at physical seg q ^ ((r>>1)&3).
// global_load_lds dest must stay linear, so the permutation is applied to the per-lane
// GLOBAL source in STAGE (inverse = same XOR), and on the read address. Lane spans become
// {0,4,1,5,2,6,3,7} within each 8-lane group -> conflict-free. (row>>1)&3 == (lrow>>1)&3
// for all fragment rows (bases are multiples of 16), so the read XOR is one VALU op.
// Data->MFMA mapping and accumulation order unchanged -> bit-identical output.
// cur/outb never alias (hb0/hb1 ping-pong in launcher).
// A: rows from m (ks<8) then cur (ks>=8), both [NPAD][256] bf16 row-major.
// B: wT layer slice [n=256][k=512] bf16, k-contiguous. Wave w owns cols w*64..w*64+63.
// fin=0: store h as bf16 (outb) AND fp8 (hqb). fin=1: sigmoid, dot wo + bias -> out[row].

__global__ __launch_bounds__(256, 4) void gemm_kernel(const u16* __restrict__ mA,
                                                      const u16* __restrict__ cur,
                                                      const u16* __restrict__ wT,
                                                      u16* __restrict__ outb,
                                                      unsigned char* __restrict__ hqb,
                                                      const float* __restrict__ wo,
                                                      const float* __restrict__ bo,
                                                      float* __restrict__ out,
                                                      int n, int apply_sigmoid, int fin) {
    __shared__ u16 lA[2][64 * 32];     // [buf][row*32 + seg*8]  4KB each (seg XOR-swizzled)
    __shared__ u16 lB[2][256 * 32];    // [buf][row*32 + seg*8] 16KB each (seg XOR-swizzled)
    __shared__ float lO[4][64];
    int r0 = blockIdx.x * 64;
    int tid = threadIdx.x;
    int lane = tid & 63;
    int w = tid >> 6;                  // wave id = col group (cols w*64..)
    int lrow = lane & 15, quad = lane >> 4;
    int xsw = (lrow >> 1) & 3;         // read-side swizzle term

    f32x4 acc[4][4] = {};

    // stage 32-wide K-step ks into LDS buffer buf (5 x global_load_lds per thread);
    // physical slot (row, sp) receives logical seg sp ^ ((row>>1)&3) from global.
    auto STAGE = [&](int buf, int ks) {
        const u16* srcA = (ks < 8) ? mA : cur;
        int kk = (ks * 32) & 255;
        {
            int li = tid;                  // 0..255 -> 64 rows x 4 segs
            int row = li >> 2;
            int sp = li & 3;
            int sl = sp ^ ((row >> 1) & 3);
            const u16* gA = srcA + (size_t)(r0 + row) * 256 + kk + sl * 8;
            __builtin_amdgcn_global_load_lds(
                (__attribute__((address_space(1))) u32*)(gA),
                (__attribute__((address_space(3))) u32*)(&lA[buf][(size_t)li * 8]), 16, 0, 0);
        }
#pragma unroll
        for (int p = 0; p < 4; ++p) {
            int li = p * 256 + tid;        // 0..1023 -> 256 rows x 4 segs
            int row = li >> 2;
            int sp = li & 3;
            int sl = sp ^ ((row >> 1) & 3);
            const u16* gB = wT + (size_t)row * 512 + ks * 32 + sl * 8;
            __builtin_amdgcn_global_load_lds(
                (__attribute__((address_space(1))) u32*)(gB),
                (__attribute__((address_space(3))) u32*)(&lB[buf][(size_t)li * 8]), 16, 0, 0);
        }
    };

    STAGE(0, 0);
    int buf = 0;
#pragma unroll
    for (int ks = 0; ks < 16; ++ks) {
        if (ks < 15) {
            STAGE(buf ^ 1, ks + 1);        // 5 prefetch loads now in flight
            // wait for the 5 OLDER loads (current buf); keep prefetch outstanding
            asm volatile("s_waitcnt vmcnt(5)" ::: "memory");
        } else {
            asm volatile("s_waitcnt vmcnt(0)" ::: "memory");
        }
        __builtin_amdgcn_sched_barrier(0);
        asm volatile("s_barrier" ::: "memory");   // all waves' buf data landed

        short8 a[4], b[4];
#pragma unroll
        for (int rt = 0; rt < 4; ++rt)
            a[rt] = *(const short8*)&lA[buf][(size_t)(rt * 16 + lrow) * 32 + (quad ^ xsw) * 8];
#pragma unroll
        for (int ct = 0; ct < 4; ++ct)
            b[ct] = *(const short8*)&lB[buf][(size_t)(w * 64 + ct * 16 + lrow) * 32 + (quad ^ xsw) * 8];
#pragma unroll
        for (int rt = 0; rt < 4; ++rt)
#pragma unroll
            for (int ct = 0; ct < 4; ++ct)
                acc[rt][ct] = __builtin_amdgcn_mfma_f32_16x16x32_bf16(a[rt], b[ct], acc[rt][ct], 0, 0, 0);

        asm volatile("s_waitcnt lgkmcnt(0)" ::: "memory");  // my ds_reads of buf done
        __builtin_amdgcn_sched_barrier(0);
        asm volatile("s_barrier" ::: "memory");   // everyone done reading buf -> safe to overwrite
        buf ^= 1;
    }

    if (!fin) {
#pragma unroll
        for (int rt = 0; rt < 4; ++rt) {
            int rbase = r0 + rt * 16 + quad * 4;
#pragma unroll
            for (int r = 0; r < 4; ++r) {
                int row = rbase + r;
                if (row < n) {
#pragma unroll
                    for (int ct = 0; ct < 4; ++ct) {
                        float v = acc[rt][ct][r];
                        if (apply_sigmoid) v = 1.0f / (1.0f + __expf(-v));
                        int col = w * 64 + ct * 16 + lrow;
                        outb[(size_t)row * 256 + col] = f2bf(v);
                        // fused fp8 emit (replaces a separate cvt_h pass)
                        u32 wq = (u32)__builtin_amdgcn_cvt_pk_fp8_f32(v, v, 0, false);
                        hqb[(size_t)row * 256 + col] = (unsigned char)(wq & 0xff);
                    }
                }
            }
        }
    } else {
        // final layer: sigmoid then dot with wo, reduce, write out
        float wv[4];
#pragma unroll
        for (int ct = 0; ct < 4; ++ct) wv[ct] = wo[w * 64 + ct * 16 + lrow];
#pragma unroll
        for (int rt = 0; rt < 4; ++rt) {
#pragma unroll
            for (int r = 0; r < 4; ++r) {
                float s = 0.f;
#pragma unroll
                for (int ct = 0; ct < 4; ++ct) {
                    float v = acc[rt][ct][r];
                    v = 1.0f / (1.0f + __expf(-v));
                    s += v * wv[ct];
                }
                // reduce across the 16 lanes (lrow bits 0..3) sharing this row
                s += __shfl_xor(s, 1);
                s += __shfl_xor(s, 2);
                s += __shfl_xor(s, 4);
                s += __shfl_xor(s, 8);
                if (lrow == 0) {
                    int rowlocal = rt * 16 + quad * 4 + r;
                    lO[w][rowlocal] = s;
                }
            }
        }
        __syncthreads();
        if (tid < 64) {
            int row = r0 + tid;
            if (row < n)
                out[row] = lO[0][tid] + lO[1][tid] + lO[2][tid] + lO[3][tid] + bo[0];
        }
    }
}

// ---------------- launch ----------------

extern "C" void kernel_launch(void* const* d_in, const int* in_sizes, int n_in,
                              void* d_out, int out_size, void* d_ws, size_t ws_size,
                              hipStream_t stream) {
    const float* x  = (const float*)d_in[0];
    const int*   ei = (const int*)d_in[1];
    const float* WA = (const float*)d_in[2];
    const float* WB = (const float*)d_in[3];
    const float* As = (const float*)d_in[4];
    const float* Bs = (const float*)d_in[5];
    const float* Wo = (const float*)d_in[6];
    const float* bo = (const float*)d_in[7];
    float* out = (float*)d_out;

    const int H = 256;
    int N = in_sizes[0] / H;
    int E = in_sizes[1] / 2;
    int L = in_sizes[4] / (H * H);
    int NPAD = (N + 127) & ~127;
    int NB = (N + 255) >> 8;           // coarse buckets (requires N <= 65536)

    char* wsp = (char*)d_ws;
    size_t off = 0;
    auto alloc = [&](size_t b) { size_t o = off; off += (b + 255) & ~(size_t)255; return o; };
    int*   rowptr = (int*)(wsp + alloc((size_t)(NPAD + 1) * 4));
    int*   ccnt   = (int*)(wsp + alloc(2048));      // ccnt[256] + cfill[256] contiguous
    int*   cfill  = ccnt + 256;
    int*   cbase  = (int*)(wsp + alloc(1032 + 256));
    float* invd   = (float*)(wsp + alloc((size_t)NPAD * 4));
    int*   srcs   = (int*)(wsp + alloc((size_t)E * 4));
    u16*   xb     = (u16*)(wsp + alloc((size_t)NPAD * H * 2));
    u16*   hb0    = (u16*)(wsp + alloc((size_t)NPAD * H * 2));  // h ping
    u16*   hb1    = (u16*)(wsp + alloc((size_t)NPAD * H * 2));  // h pong
    u16*   mb     = (u16*)(wsp + alloc((size_t)NPAD * H * 2));
    u32*   xq     = (u32*)(wsp + alloc((size_t)NPAD * H));      // fp8 x
    u32*   hq     = (u32*)(wsp + alloc((size_t)NPAD * H));      // fp8 h (gemm epilogue)
    u16*   wT     = (u16*)(wsp + alloc((size_t)(L + 1) * 512 * 256 * 2));
    // tmp (packed coarse-sorted edges) aliases mb: dead until first agg writes mb
    u32*   tmp    = (u32*)mb;

    const int* esrc = ei;
    const int* edst = ei + E;

    hipMemsetAsync(ccnt, 0, 2048, stream);

    int gridE = (E + 4095) / 4096;
    int nx = NPAD / 4;
    int nw = ((L + 1) * 512 * 256 + 255) / 256;
    prep_kernel<<<nx + nw + gridE, 256, 0, stream>>>(x, xb, xq, N, nx,
                                                     WA, WB, As, Bs, wT, L + 1, nw,
                                                     edst, ccnt, E, NB);
    scan_coarse_kernel<<<1, 256, 0, stream>>>(ccnt, cbase, rowptr, NB, N, E);
    passA_kernel<<<gridE, 256, 0, stream>>>(esrc, edst, cbase, cfill, tmp, E, NB);
    passB_kernel<<<NB, 256, 0, stream>>>(tmp, cbase, rowptr, invd, srcs, N);

    const u16* cur = xb;
    const unsigned char* curq = (const unsigned char*)xq;
    u16* hnext = hb0;
    for (int s = 0; s <= L; ++s) {
        int fin = (s == L) ? 1 : 0;
        agg_kernel<<<NPAD / 4, 256, 0, stream>>>(curq, mb, rowptr, srcs, invd, N, NPAD);
        gemm_kernel<<<NPAD / 64, 256, 0, stream>>>(mb, cur, wT + (size_t)s * 512 * 256, hnext,
                                                   (unsigned char*)hq, Wo, bo, out, N,
                                                   s > 0 ? 1 : 0, fin);
        if (!fin) {
            cur = hnext;
            curq = (const unsigned char*)hq;
            hnext = (hnext == hb0) ? hb1 : hb0;
        }
    }
}